// Round 11
// baseline (57.963 us; speedup 1.0000x reference)
//
#include <hip/hip_runtime.h>
#include <math.h>

#define L 4096
#define C2 32
#define CTOT 64
#define BB 4
#define NG 4
#define NSAMP 2048
#define TPB 256              // 4 waves = 4 sample-quarters (sh) of one row-tile
#define ROWSPB 32
#define TPW 16               // tiles per wave (512 samples)
#define WS_NEED (64 * 3072)  // 64 tiles x 3 KB presplit B-data

typedef _Float16 half8 __attribute__((ext_vector_type(8)));
typedef float f32x16 __attribute__((ext_vector_type(16)));

__device__ __forceinline__ void split3(float x, _Float16& h, _Float16& m, _Float16& l) {
    h = (_Float16)x; float r1 = x - (float)h;
    m = (_Float16)r1; float r2 = r1 - (float)m;
    l = (_Float16)r2;
}

// ---- kernel 1: split prior samples into 3-level f16 B-layout in ws ----
// tile = n>>5 (3072 B each): level*1024 + kh*512 + col*16; kh0 = s^2, kh1 = s.
__global__ __launch_bounds__(256) void presplit_kernel(
    const float* __restrict__ prior, char* __restrict__ ws)
{
    int n = blockIdx.x * 256 + threadIdx.x;
    const float4* p4 = (const float4*)prior;
    float4 u = p4[2 * n], v = p4[2 * n + 1];
    float s[8] = {u.x, u.y, u.z, u.w, v.x, v.y, v.z, v.w};
    half8 qh, qm, ql, vh, vm, vl;
    #pragma unroll
    for (int g = 0; g < 8; ++g) {
        _Float16 hh, mm, ll;
        split3(s[g] * s[g], hh, mm, ll);
        qh[g] = hh; qm[g] = mm; ql[g] = ll;
        split3(s[g], hh, mm, ll);
        vh[g] = hh; vm[g] = mm; vl[g] = ll;
    }
    char* tb = ws + (size_t)(n >> 5) * 3072 + (size_t)(n & 31) * 16;
    *(half8*)(tb + 0)    = qh;
    *(half8*)(tb + 512)  = vh;
    *(half8*)(tb + 1024) = qm;
    *(half8*)(tb + 1536) = vm;
    *(half8*)(tb + 2048) = ql;
    *(half8*)(tb + 2560) = vl;
}

// ---- kernel 2: 32x32x16 f16 MFMA score+argmax (3-way split, 6 terms —
// numerics identical to R7..R10, absmax 0). Block = one 32-row tile; wave sh
// (0..3) scans 512 samples (16 tiles) read directly from L2-resident ws.
// 8192 waves = 8/SIMD. Argmax tracks tile id tt (inline const) not n.
// A-frag: lane holds A[row=col][k=kh*8+g], k0-7 = ca, k8-15 = cb.
// D: col=lane&31, row=(reg&3)+8*(reg>>2)+4*(lane>>5) (HW-validated R8..R10).
__global__ __launch_bounds__(TPB) void gqreg_main(
    const float* __restrict__ z, const float* __restrict__ prior,
    float* __restrict__ out, const char* __restrict__ wsb, int use_ws)
{
    __shared__ float mbB[4][2][16];   // [sh][kh][j]
    __shared__ int   mbI[4][2][16];

    const int tid = threadIdx.x;
    const int lane = tid & 63;
    const int sh = tid >> 6;
    const int col = lane & 31;
    const int kh = lane >> 5;
    const float4* p4 = (const float4*)prior;

    // ---- A coefficients (all 4 waves same rows; redundant but one-off) ----
    const int rowbase = blockIdx.x * ROWSPB;
    half8 ah, am, al;
    {
        int r = rowbase + col;
        int b = r >> 14, pos = (r >> 2) & (L - 1), ns = r & 3;
        const float* zb = z + (size_t)b * CTOT * L + pos;
        #pragma unroll
        for (int g = 0; g < 8; ++g) {
            float mu = zb[(size_t)(g * NG + ns) * L];
            float lv = zb[(size_t)(C2 + g * NG + ns) * L];
            lv = fminf(fmaxf(lv, -30.f), 20.f);
            float iv = expf(-lv);
            float x = kh ? (mu * iv) : (0.5f - 0.5f * iv);
            _Float16 xh, xm, xl;
            split3(x, xh, xm, xl);
            ah[g] = xh; am[g] = xm; al[g] = xl;
        }
    }

    float best[16];
    int bidx[16];
    #pragma unroll
    for (int j = 0; j < 16; ++j) { best[j] = -INFINITY; bidx[j] = 0; }
    const f32x16 z16 = {};

    if (use_ws) {
        const char* tb = wsb + (size_t)(sh * TPW) * 3072 + (size_t)(kh * 512 + col * 16);
        #pragma unroll 2
        for (int t = 0; t < TPW; ++t) {
            half8 Bh = *(const half8*)(tb + 0);
            half8 Bm = *(const half8*)(tb + 1024);
            half8 Bl = *(const half8*)(tb + 2048);
            tb += 3072;
            const int tt = sh * TPW + t;   // 0..63, inline-const in cndmask
            f32x16 acc;
            acc = __builtin_amdgcn_mfma_f32_32x32x16_f16(ah, Bh, z16, 0, 0, 0);
            acc = __builtin_amdgcn_mfma_f32_32x32x16_f16(ah, Bm, acc, 0, 0, 0);
            acc = __builtin_amdgcn_mfma_f32_32x32x16_f16(am, Bh, acc, 0, 0, 0);
            acc = __builtin_amdgcn_mfma_f32_32x32x16_f16(am, Bm, acc, 0, 0, 0);
            acc = __builtin_amdgcn_mfma_f32_32x32x16_f16(ah, Bl, acc, 0, 0, 0);
            acc = __builtin_amdgcn_mfma_f32_32x32x16_f16(al, Bh, acc, 0, 0, 0);
            #pragma unroll
            for (int j = 0; j < 16; ++j) {
                bool gt = acc[j] > best[j];
                best[j] = gt ? acc[j] : best[j];
                bidx[j] = gt ? tt : bidx[j];
            }
        }
    } else {
        // fallback: split B in-VALU per tile (no ws)
        #pragma unroll 2
        for (int t = 0; t < TPW; ++t) {
            const int tt = sh * TPW + t;
            int n = tt * 32 + col;
            float4 u = p4[2 * n], v = p4[2 * n + 1];
            float sv[8] = {u.x, u.y, u.z, u.w, v.x, v.y, v.z, v.w};
            half8 Bh, Bm, Bl;
            #pragma unroll
            for (int g = 0; g < 8; ++g) {
                float x = kh ? sv[g] : sv[g] * sv[g];
                _Float16 hh, mm, ll;
                split3(x, hh, mm, ll);
                Bh[g] = hh; Bm[g] = mm; Bl[g] = ll;
            }
            f32x16 acc;
            acc = __builtin_amdgcn_mfma_f32_32x32x16_f16(ah, Bh, z16, 0, 0, 0);
            acc = __builtin_amdgcn_mfma_f32_32x32x16_f16(ah, Bm, acc, 0, 0, 0);
            acc = __builtin_amdgcn_mfma_f32_32x32x16_f16(am, Bh, acc, 0, 0, 0);
            acc = __builtin_amdgcn_mfma_f32_32x32x16_f16(am, Bm, acc, 0, 0, 0);
            acc = __builtin_amdgcn_mfma_f32_32x32x16_f16(ah, Bl, acc, 0, 0, 0);
            acc = __builtin_amdgcn_mfma_f32_32x32x16_f16(al, Bh, acc, 0, 0, 0);
            #pragma unroll
            for (int j = 0; j < 16; ++j) {
                bool gt = acc[j] > best[j];
                best[j] = gt ? acc[j] : best[j];
                bidx[j] = gt ? tt : bidx[j];
            }
        }
    }

    // ---- recover n and reduce across 32 cols (tie -> lowest n) ----
    int bn[16];
    #pragma unroll
    for (int j = 0; j < 16; ++j) bn[j] = bidx[j] * 32 + col;
    #pragma unroll
    for (int j = 0; j < 16; ++j) {
        #pragma unroll
        for (int m = 1; m < 32; m <<= 1) {
            float os = __shfl_xor(best[j], m, 64);
            int oi = __shfl_xor(bn[j], m, 64);
            if (os > best[j] || (os == best[j] && oi < bn[j])) {
                best[j] = os; bn[j] = oi;
            }
        }
    }

    // ---- post per-wave results (2 lanes/wave active) ----
    if (col == 0) {
        #pragma unroll
        for (int j = 0; j < 16; ++j) {
            mbB[sh][kh][j] = best[j];
            mbI[sh][kh][j] = bn[j];
        }
    }
    __syncthreads();

    // ---- wave 0 merges sample-quarters (sh ascending = n ascending; strict >
    //      keeps lowest) and writes the 32 rows, one per lane ----
    if (tid < 32) {
        int rr = tid;
        int kh_o = (rr >> 2) & 1;
        int j_o = (rr & 3) | ((rr >> 3) << 2);
        float bv = mbB[0][kh_o][j_o];
        int n = mbI[0][kh_o][j_o];
        #pragma unroll
        for (int s = 1; s < 4; ++s) {
            float ob = mbB[s][kh_o][j_o];
            int oi = mbI[s][kh_o][j_o];
            if (ob > bv) { bv = ob; n = oi; }
        }
        int r = rowbase + rr;
        int b = r >> 14, pos = (r >> 2) & (L - 1), ns = r & 3;
        out[(size_t)BB * C2 * L + ((size_t)b * NG + ns) * L + pos] = (float)n;
        float4 uu = p4[2 * n], vv = p4[2 * n + 1];
        float sv[8] = {uu.x, uu.y, uu.z, uu.w, vv.x, vv.y, vv.z, vv.w};
        #pragma unroll
        for (int g = 0; g < 8; ++g) {
            out[((size_t)b * C2 + g * NG + ns) * L + pos] = sv[g];
        }
    }
}

extern "C" void kernel_launch(void* const* d_in, const int* in_sizes, int n_in,
                              void* d_out, int out_size, void* d_ws, size_t ws_size,
                              hipStream_t stream) {
    const float* z = (const float*)d_in[0];
    const float* prior = (const float*)d_in[1];
    float* out = (float*)d_out;
    char* ws = (char*)d_ws;
    int use_ws = (ws_size >= (size_t)WS_NEED) ? 1 : 0;

    if (use_ws) {
        hipLaunchKernelGGL(presplit_kernel, dim3(NSAMP / 256), dim3(256), 0, stream,
                           prior, ws);
    }
    hipLaunchKernelGGL(gqreg_main, dim3((BB * L * NG) / ROWSPB), dim3(TPB), 0, stream,
                       z, prior, out, (const char*)ws, use_ws);
}

// Round 12
// 49.847 us; speedup vs baseline: 1.1628x; 1.1628x over previous
//
#include <hip/hip_runtime.h>
#include <math.h>

#define L 4096
#define C2 32
#define CTOT 64
#define BB 4
#define NG 4
#define NSAMP 2048
#define TPB 256
#define ROWSPB 64            // per block: 2 row-tiles x 32 rows
#define AOFF 196608          // B-ws: 64 tiles x 3072 B; A-ws follows
#define WS_B 196608
#define WS_A (196608 + 6291456)   // + 2048 rowtiles x 2 kh x 32 col x 48 B

typedef _Float16 half8 __attribute__((ext_vector_type(8)));
typedef float f32x16 __attribute__((ext_vector_type(16)));

__device__ __forceinline__ void split3(float x, _Float16& h, _Float16& m, _Float16& l) {
    h = (_Float16)x; float r1 = x - (float)h;
    m = (_Float16)r1; float r2 = r1 - (float)m;
    l = (_Float16)r2;
}

// ---- prep: blocks 0..7 presplit B samples; blocks 8..263 precompute A-frags ----
// B tile = n>>5 (3072 B): level*1024 + kh*512 + col*16; kh0 = s^2, kh1 = s.
// A frag for (rowtile rtg, kh, col): 48 B = {h,m,l} half8 over g; row = rtg*32+col,
// k = kh*8+g; kh0 = ca = 0.5*(1-iv), kh1 = cb = mu*iv.
__global__ __launch_bounds__(256) void prep_kernel(
    const float* __restrict__ z, const float* __restrict__ prior,
    char* __restrict__ ws)
{
    const int blk = blockIdx.x, tid = threadIdx.x;
    if (blk < 8) {
        int n = blk * 256 + tid;
        const float4* p4 = (const float4*)prior;
        float4 u = p4[2 * n], v = p4[2 * n + 1];
        float s[8] = {u.x, u.y, u.z, u.w, v.x, v.y, v.z, v.w};
        half8 qh, qm, ql, vh, vm, vl;
        #pragma unroll
        for (int g = 0; g < 8; ++g) {
            _Float16 hh, mm, ll;
            split3(s[g] * s[g], hh, mm, ll);
            qh[g] = hh; qm[g] = mm; ql[g] = ll;
            split3(s[g], hh, mm, ll);
            vh[g] = hh; vm[g] = mm; vl[g] = ll;
        }
        char* tb = ws + (size_t)(n >> 5) * 3072 + (size_t)(n & 31) * 16;
        *(half8*)(tb + 0)    = qh;
        *(half8*)(tb + 512)  = vh;
        *(half8*)(tb + 1024) = qm;
        *(half8*)(tb + 1536) = vm;
        *(half8*)(tb + 2048) = ql;
        *(half8*)(tb + 2560) = vl;
    } else {
        int r = (blk - 8) * 256 + tid;            // global row 0..65535
        int rtg = r >> 5, col = r & 31;
        int b = r >> 14, pos = (r >> 2) & (L - 1), ns = r & 3;
        const float* zb = z + (size_t)b * CTOT * L + pos;
        half8 cah, cam, cal, cbh, cbm, cbl;
        #pragma unroll
        for (int g = 0; g < 8; ++g) {
            float mu = zb[(size_t)(g * NG + ns) * L];
            float lv = zb[(size_t)(C2 + g * NG + ns) * L];
            lv = fminf(fmaxf(lv, -30.f), 20.f);
            float iv = expf(-lv);
            _Float16 hh, mm, ll;
            split3(0.5f - 0.5f * iv, hh, mm, ll);
            cah[g] = hh; cam[g] = mm; cal[g] = ll;
            split3(mu * iv, hh, mm, ll);
            cbh[g] = hh; cbm[g] = mm; cbl[g] = ll;
        }
        char* b0 = ws + AOFF + (size_t)(((rtg * 2 + 0) * 32 + col)) * 48;
        *(half8*)(b0 + 0) = cah; *(half8*)(b0 + 16) = cam; *(half8*)(b0 + 32) = cal;
        char* b1 = ws + AOFF + (size_t)(((rtg * 2 + 1) * 32 + col)) * 48;
        *(half8*)(b1 + 0) = cbh; *(half8*)(b1 + 16) = cbm; *(half8*)(b1 + 32) = cbl;
    }
}

// ---- main: 32x32x16 f16 MFMA score+argmax (3-way split, 6 terms — numerics
// identical to R7..R11, absmax 0). Block = 2 row-tiles x 2 sample-halves
// (4 waves). Wave scans 32 tiles (1024 samples) as DUAL independent MFMA
// chains (12 in flight). A-frags + B-frags read from L2-resident ws; no
// per-wave coefficient math, no main-loop barriers.
// D: col=lane&31, row=(reg&3)+8*(reg>>2)+4*(lane>>5) (HW-validated R8..R11).
__global__ __launch_bounds__(TPB) void gqreg_main(
    const float* __restrict__ z, const float* __restrict__ prior,
    float* __restrict__ out, const char* __restrict__ wsb, int bws, int aws)
{
    __shared__ float mbB[2][2][2][16];   // [rt][sh][kh][j]
    __shared__ int   mbI[2][2][2][16];

    const int tid = threadIdx.x;
    const int lane = tid & 63;
    const int w = tid >> 6;
    const int rt = w >> 1;
    const int sh = w & 1;
    const int col = lane & 31;
    const int kh = lane >> 5;
    const float4* p4 = (const float4*)prior;
    const int rowbase = blockIdx.x * ROWSPB + rt * 32;

    // ---- A fragments ----
    half8 ah, am, al;
    if (aws) {
        int rtg = blockIdx.x * 2 + rt;
        const char* ab = wsb + AOFF + (size_t)((rtg * 2 + kh) * 32 + col) * 48;
        ah = *(const half8*)(ab + 0);
        am = *(const half8*)(ab + 16);
        al = *(const half8*)(ab + 32);
    } else {
        int r = rowbase + col;
        int b = r >> 14, pos = (r >> 2) & (L - 1), ns = r & 3;
        const float* zb = z + (size_t)b * CTOT * L + pos;
        #pragma unroll
        for (int g = 0; g < 8; ++g) {
            float mu = zb[(size_t)(g * NG + ns) * L];
            float lv = zb[(size_t)(C2 + g * NG + ns) * L];
            lv = fminf(fmaxf(lv, -30.f), 20.f);
            float iv = expf(-lv);
            float x = kh ? (mu * iv) : (0.5f - 0.5f * iv);
            _Float16 xh, xm, xl;
            split3(x, xh, xm, xl);
            ah[g] = xh; am[g] = xm; al[g] = xl;
        }
    }

    float best[16];
    int bt[16];
    #pragma unroll
    for (int j = 0; j < 16; ++j) { best[j] = -INFINITY; bt[j] = 0; }
    const f32x16 z16 = {};

    if (bws) {
        const char* base = wsb + (size_t)(kh * 512 + col * 16);
        #pragma unroll 4
        for (int t = 0; t < 32; t += 2) {
            const int tt0 = sh * 32 + t, tt1 = tt0 + 1;
            const char* p0 = base + (size_t)tt0 * 3072;
            const char* p1 = base + (size_t)tt1 * 3072;
            half8 B0h = *(const half8*)(p0 + 0);
            half8 B0m = *(const half8*)(p0 + 1024);
            half8 B0l = *(const half8*)(p0 + 2048);
            half8 B1h = *(const half8*)(p1 + 0);
            half8 B1m = *(const half8*)(p1 + 1024);
            half8 B1l = *(const half8*)(p1 + 2048);
            f32x16 a0, a1;
            a0 = __builtin_amdgcn_mfma_f32_32x32x16_f16(ah, B0h, z16, 0, 0, 0);
            a1 = __builtin_amdgcn_mfma_f32_32x32x16_f16(ah, B1h, z16, 0, 0, 0);
            a0 = __builtin_amdgcn_mfma_f32_32x32x16_f16(ah, B0m, a0, 0, 0, 0);
            a1 = __builtin_amdgcn_mfma_f32_32x32x16_f16(ah, B1m, a1, 0, 0, 0);
            a0 = __builtin_amdgcn_mfma_f32_32x32x16_f16(am, B0h, a0, 0, 0, 0);
            a1 = __builtin_amdgcn_mfma_f32_32x32x16_f16(am, B1h, a1, 0, 0, 0);
            a0 = __builtin_amdgcn_mfma_f32_32x32x16_f16(am, B0m, a0, 0, 0, 0);
            a1 = __builtin_amdgcn_mfma_f32_32x32x16_f16(am, B1m, a1, 0, 0, 0);
            a0 = __builtin_amdgcn_mfma_f32_32x32x16_f16(ah, B0l, a0, 0, 0, 0);
            a1 = __builtin_amdgcn_mfma_f32_32x32x16_f16(ah, B1l, a1, 0, 0, 0);
            a0 = __builtin_amdgcn_mfma_f32_32x32x16_f16(al, B0h, a0, 0, 0, 0);
            a1 = __builtin_amdgcn_mfma_f32_32x32x16_f16(al, B1h, a1, 0, 0, 0);
            #pragma unroll
            for (int j = 0; j < 16; ++j) {
                bool g0 = a0[j] > best[j];
                best[j] = g0 ? a0[j] : best[j];
                bt[j]   = g0 ? tt0 : bt[j];
                bool g1 = a1[j] > best[j];
                best[j] = g1 ? a1[j] : best[j];
                bt[j]   = g1 ? tt1 : bt[j];
            }
        }
    } else {
        // fallback: split B in-VALU per tile
        #pragma unroll 2
        for (int t = 0; t < 32; ++t) {
            const int tt = sh * 32 + t;
            int n = tt * 32 + col;
            float4 u = p4[2 * n], v = p4[2 * n + 1];
            float sv[8] = {u.x, u.y, u.z, u.w, v.x, v.y, v.z, v.w};
            half8 Bh, Bm, Bl;
            #pragma unroll
            for (int g = 0; g < 8; ++g) {
                float x = kh ? sv[g] : sv[g] * sv[g];
                _Float16 hh, mm, ll;
                split3(x, hh, mm, ll);
                Bh[g] = hh; Bm[g] = mm; Bl[g] = ll;
            }
            f32x16 acc;
            acc = __builtin_amdgcn_mfma_f32_32x32x16_f16(ah, Bh, z16, 0, 0, 0);
            acc = __builtin_amdgcn_mfma_f32_32x32x16_f16(ah, Bm, acc, 0, 0, 0);
            acc = __builtin_amdgcn_mfma_f32_32x32x16_f16(am, Bh, acc, 0, 0, 0);
            acc = __builtin_amdgcn_mfma_f32_32x32x16_f16(am, Bm, acc, 0, 0, 0);
            acc = __builtin_amdgcn_mfma_f32_32x32x16_f16(ah, Bl, acc, 0, 0, 0);
            acc = __builtin_amdgcn_mfma_f32_32x32x16_f16(al, Bh, acc, 0, 0, 0);
            #pragma unroll
            for (int j = 0; j < 16; ++j) {
                bool gt = acc[j] > best[j];
                best[j] = gt ? acc[j] : best[j];
                bt[j]   = gt ? tt : bt[j];
            }
        }
    }

    // ---- recover n; cross-col reduce within kh half (tie -> lowest n) ----
    int bn[16];
    #pragma unroll
    for (int j = 0; j < 16; ++j) bn[j] = bt[j] * 32 + col;
    #pragma unroll
    for (int j = 0; j < 16; ++j) {
        #pragma unroll
        for (int m = 1; m < 32; m <<= 1) {
            float os = __shfl_xor(best[j], m, 64);
            int oi = __shfl_xor(bn[j], m, 64);
            if (os > best[j] || (os == best[j] && oi < bn[j])) {
                best[j] = os; bn[j] = oi;
            }
        }
    }

    // ---- post per-wave results (2 active lanes/wave -> no conflicts) ----
    if (col == 0) {
        #pragma unroll
        for (int j = 0; j < 16; ++j) {
            mbB[rt][sh][kh][j] = best[j];
            mbI[rt][sh][kh][j] = bn[j];
        }
    }
    __syncthreads();

    // ---- wave 0 merges sample-halves (sh0 n < sh1 n: strict > keeps lowest)
    //      and writes all 64 rows, one per lane ----
    if (w == 0) {
        int rt_o = lane >> 5;
        int rr = lane & 31;
        int kh_o = (rr >> 2) & 1;
        int j_o = (rr & 3) | ((rr >> 3) << 2);
        float b0 = mbB[rt_o][0][kh_o][j_o];
        int i0 = mbI[rt_o][0][kh_o][j_o];
        float b1 = mbB[rt_o][1][kh_o][j_o];
        int i1 = mbI[rt_o][1][kh_o][j_o];
        int n = (b1 > b0) ? i1 : i0;
        int r = blockIdx.x * ROWSPB + rt_o * 32 + rr;
        int b = r >> 14, pos = (r >> 2) & (L - 1), ns = r & 3;
        out[(size_t)BB * C2 * L + ((size_t)b * NG + ns) * L + pos] = (float)n;
        float4 uu = p4[2 * n], vv = p4[2 * n + 1];
        float sv[8] = {uu.x, uu.y, uu.z, uu.w, vv.x, vv.y, vv.z, vv.w};
        #pragma unroll
        for (int g = 0; g < 8; ++g) {
            out[((size_t)b * C2 + g * NG + ns) * L + pos] = sv[g];
        }
    }
}

extern "C" void kernel_launch(void* const* d_in, const int* in_sizes, int n_in,
                              void* d_out, int out_size, void* d_ws, size_t ws_size,
                              hipStream_t stream) {
    const float* z = (const float*)d_in[0];
    const float* prior = (const float*)d_in[1];
    float* out = (float*)d_out;
    char* ws = (char*)d_ws;
    int bws = (ws_size >= (size_t)WS_B) ? 1 : 0;
    int aws = (ws_size >= (size_t)WS_A) ? 1 : 0;

    if (bws) {
        int nprep = 8 + (aws ? 256 : 0);
        hipLaunchKernelGGL(prep_kernel, dim3(nprep), dim3(256), 0, stream,
                           z, prior, ws);
    }
    hipLaunchKernelGGL(gqreg_main, dim3((BB * L * NG) / ROWSPB), dim3(TPB), 0, stream,
                       z, prior, out, (const char*)ws, bws, aws);
}